// Round 1
// baseline (135.055 us; speedup 1.0000x reference)
//
#include <hip/hip_runtime.h>
#include <math.h>

#define BB 64
#define SS 2048
#define HH 1024
#define PP 8
#define SPLIT 32
#define ROWS (SS / SPLIT)   // 64

// ---------------- Kernel 1: partial mean-pool over S ----------------
// grid = BB*SPLIT (2048) blocks, 256 threads. Each block sums ROWS=64 rows of
// one (b, s-chunk) into a partial row in workspace. float4 loads: 1KB/wave/instr.
__global__ __launch_bounds__(256) void pool_partial_k(const float* __restrict__ hs,
                                                      float* __restrict__ part) {
    int blk = blockIdx.x;
    int b  = blk / SPLIT;
    int sp = blk % SPLIT;
    int t  = threadIdx.x;  // 0..255 -> covers HH via float4
    const float4* base = reinterpret_cast<const float4*>(
        hs + (size_t)b * SS * HH + (size_t)sp * ROWS * HH);
    float4 acc = make_float4(0.f, 0.f, 0.f, 0.f);
    #pragma unroll 8
    for (int s = 0; s < ROWS; ++s) {
        float4 v = base[(size_t)s * (HH / 4) + t];
        acc.x += v.x; acc.y += v.y; acc.z += v.z; acc.w += v.w;
    }
    reinterpret_cast<float4*>(part)[(size_t)blk * (HH / 4) + t] = acc;
}

// ---------------- Kernel 2: finish pooling ----------------
// 65536 outputs; each thread sums SPLIT partials and scales by 1/S.
__global__ __launch_bounds__(256) void pool_finish_k(const float* __restrict__ part,
                                                     float* __restrict__ pooled) {
    int idx = blockIdx.x * 256 + threadIdx.x;   // 0..BB*HH-1
    int b = idx >> 10;
    int h = idx & 1023;
    float s = 0.f;
    #pragma unroll
    for (int sp = 0; sp < SPLIT; ++sp)
        s += part[((size_t)b * SPLIT + sp) * HH + h];
    pooled[idx] = s * (1.0f / (float)SS);
}

// ---------------- Kernel 3: h = silu(pooled @ W1^T + b1) ----------------
// grid = BB*4 blocks (b, 256-output chunk), 256 threads = 4 waves.
// Wave computes 64 outputs; for each output the 64 lanes split the K=1024 dot
// (coalesced float4 W1 row reads), butterfly-reduce, lane j keeps output j.
__global__ __launch_bounds__(256) void gemm1_silu_k(const float* __restrict__ pooled,
                                                    const float* __restrict__ W1,
                                                    const float* __restrict__ b1,
                                                    float* __restrict__ hbuf) {
    int b  = blockIdx.x >> 2;
    int oc = blockIdx.x & 3;
    int t  = threadIdx.x;
    int wave = t >> 6, lane = t & 63;
    __shared__ float4 spool[HH / 4];
    spool[t] = reinterpret_cast<const float4*>(pooled + (size_t)b * HH)[t];
    __syncthreads();
    float myz = 0.f;
    for (int j = 0; j < 64; ++j) {
        int o = oc * 256 + wave * 64 + j;
        const float4* wrow = reinterpret_cast<const float4*>(W1 + (size_t)o * HH);
        float s = 0.f;
        #pragma unroll
        for (int k = 0; k < 4; ++k) {
            float4 wv = wrow[lane + 64 * k];
            float4 pv = spool[lane + 64 * k];
            s += wv.x * pv.x + wv.y * pv.y + wv.z * pv.z + wv.w * pv.w;
        }
        #pragma unroll
        for (int off = 32; off; off >>= 1) s += __shfl_xor(s, off);
        if (lane == j) myz = s;   // lane j owns output j of this wave's chunk
    }
    int o = oc * 256 + wave * 64 + lane;
    float z = myz + b1[o];
    hbuf[(size_t)b * HH + o] = z / (1.f + expf(-z));   // silu, coalesced write
}

// ---------------- Kernel 4: logits, softmax, bit allocation ----------------
// grid = BB blocks, 64 threads (one wave per batch row).
__global__ __launch_bounds__(64) void head_k(const float* __restrict__ hbuf,
                                             const float* __restrict__ W2,
                                             const float* __restrict__ b2,
                                             const float* __restrict__ temp_p,
                                             const int* __restrict__ budget_p,
                                             float* __restrict__ out) {
    int b = blockIdx.x;
    int lane = threadIdx.x;
    const float4* hrow = reinterpret_cast<const float4*>(hbuf + (size_t)b * HH);
    float4 hv[4];
    #pragma unroll
    for (int k = 0; k < 4; ++k) hv[k] = hrow[lane + 64 * k];

    float logit[PP];
    #pragma unroll
    for (int p = 0; p < PP; ++p) {
        const float4* wrow = reinterpret_cast<const float4*>(W2 + (size_t)p * HH);
        float s = 0.f;
        #pragma unroll
        for (int k = 0; k < 4; ++k) {
            float4 wv = wrow[lane + 64 * k];
            s += wv.x * hv[k].x + wv.y * hv[k].y + wv.z * hv[k].z + wv.w * hv[k].w;
        }
        #pragma unroll
        for (int off = 32; off; off >>= 1) s += __shfl_xor(s, off);
        logit[p] = s + b2[p];   // all lanes hold full sum
    }

    // epilogue replicated on all lanes (identical values)
    float temp = fminf(fmaxf(temp_p[0], 0.1f), 5.0f);
    float budget = (float)budget_p[0];
    float inv_t = 1.0f / temp;
    float m = -INFINITY;
    #pragma unroll
    for (int p = 0; p < PP; ++p) { logit[p] *= inv_t; m = fmaxf(m, logit[p]); }
    float e[PP], se = 0.f;
    #pragma unroll
    for (int p = 0; p < PP; ++p) { e[p] = expf(logit[p] - m); se += e[p]; }
    float probs[PP];
    float inv_se = 1.0f / se;
    #pragma unroll
    for (int p = 0; p < PP; ++p) probs[p] = e[p] * inv_se;

    float x[PP], sx = 0.f;
    #pragma unroll
    for (int p = 0; p < PP; ++p) {
        x[p] = fminf(fmaxf(probs[p] * budget, 2.0f), 8.0f);
        sx += x[p];
    }
    float r = budget / (sx + 1e-8f);
    float bits[PP], sb = 0.f;
    #pragma unroll
    for (int p = 0; p < PP; ++p) {
        x[p] *= r;
        bits[p] = rintf(x[p]);   // round-half-even == jnp.round
        sb += bits[p];
    }
    float diff = truncf(budget - sb);
    if (diff != 0.f) {
        int idx = 0;
        if (diff > 0.f) {
            float best = bits[0];
            for (int p = 1; p < PP; ++p) if (bits[p] > best) { best = bits[p]; idx = p; }
        } else {
            float best = bits[0];
            for (int p = 1; p < PP; ++p) if (bits[p] < best) { best = bits[p]; idx = p; }
        }
        bits[idx] = fminf(fmaxf(bits[idx] + diff, 2.0f), 8.0f);
    }

    if (lane < PP)            out[b * PP + lane] = bits[lane];
    else if (lane < 2 * PP)   out[BB * PP + b * PP + (lane - PP)] = probs[lane - PP];
}

extern "C" void kernel_launch(void* const* d_in, const int* in_sizes, int n_in,
                              void* d_out, int out_size, void* d_ws, size_t ws_size,
                              hipStream_t stream) {
    const float* hs     = (const float*)d_in[0];
    const float* W1     = (const float*)d_in[1];
    const float* b1     = (const float*)d_in[2];
    const float* W2     = (const float*)d_in[3];
    const float* b2     = (const float*)d_in[4];
    const float* temp   = (const float*)d_in[5];
    const int*   budget = (const int*)d_in[6];
    float* out = (float*)d_out;

    float* ws     = (float*)d_ws;
    float* part   = ws;                                  // BB*SPLIT*HH floats (8 MB)
    float* pooled = ws + (size_t)BB * SPLIT * HH;        // BB*HH floats
    float* hbuf   = pooled + (size_t)BB * HH;            // BB*HH floats

    hipLaunchKernelGGL(pool_partial_k, dim3(BB * SPLIT), dim3(256), 0, stream, hs, part);
    hipLaunchKernelGGL(pool_finish_k,  dim3(BB * HH / 256), dim3(256), 0, stream, part, pooled);
    hipLaunchKernelGGL(gemm1_silu_k,   dim3(BB * 4), dim3(256), 0, stream, pooled, W1, b1, hbuf);
    hipLaunchKernelGGL(head_k,         dim3(BB), dim3(64), 0, stream, hbuf, W2, b2, temp, budget, out);
}

// Round 3
// 106.576 us; speedup vs baseline: 1.2672x; 1.2672x over previous
//
#include <hip/hip_runtime.h>
#include <math.h>

#define BB 64
#define SS 2048
#define HH 1024
#define PP 8
#define SPLIT 32
#define ROWS (SS / SPLIT)   // 64

typedef float vf4 __attribute__((ext_vector_type(4)));  // native vec: OK for nontemporal builtin

// ---------------- Kernel 1: partial mean-pool over S ----------------
// grid = BB*SPLIT (2048) blocks, 256 threads. Each block sums ROWS=64 rows of
// one (b, s-chunk) into a partial row in workspace. Nontemporal float4 loads
// (streaming 512MB, keep L2 clean for W1/partials); two accumulator chains.
__global__ __launch_bounds__(256) void pool_partial_k(const float* __restrict__ hs,
                                                      float* __restrict__ part) {
    int blk = blockIdx.x;
    int b  = blk / SPLIT;
    int sp = blk % SPLIT;
    int t  = threadIdx.x;  // 0..255 -> covers HH via float4
    const vf4* base = reinterpret_cast<const vf4*>(
        hs + (size_t)b * SS * HH + (size_t)sp * ROWS * HH);
    vf4 acc0 = (vf4)0.f;
    vf4 acc1 = (vf4)0.f;
    #pragma unroll 4
    for (int s = 0; s < ROWS; s += 2) {
        vf4 v0 = __builtin_nontemporal_load(&base[(size_t)s * (HH / 4) + t]);
        vf4 v1 = __builtin_nontemporal_load(&base[(size_t)(s + 1) * (HH / 4) + t]);
        acc0 += v0;
        acc1 += v1;
    }
    vf4 acc = acc0 + acc1;
    reinterpret_cast<vf4*>(part)[(size_t)blk * (HH / 4) + t] = acc;
}

// ---------------- Kernel 2: finish pooling (float4) ----------------
// BB*HH/4 = 16384 float4 outputs; each thread sums SPLIT partial float4s.
__global__ __launch_bounds__(256) void pool_finish_k(const float* __restrict__ part,
                                                     float* __restrict__ pooled) {
    int idx = blockIdx.x * 256 + threadIdx.x;   // 0..BB*HH/4-1
    int b = idx >> 8;          // 256 float4 per row
    int c = idx & 255;
    const vf4* p4 = reinterpret_cast<const vf4*>(part);
    vf4 s = (vf4)0.f;
    #pragma unroll
    for (int sp = 0; sp < SPLIT; ++sp)
        s += p4[((size_t)b * SPLIT + sp) * (HH / 4) + c];
    s *= (1.0f / (float)SS);
    reinterpret_cast<vf4*>(pooled)[idx] = s;
}

// ---------------- Kernel 3: h = silu(pooled @ W1^T + b1) ----------------
// grid = BB*16 blocks (b, 64-output chunk), 256 threads = 4 waves (4/CU -> 16 waves/CU).
// Wave computes 16 outputs; for each output the 64 lanes split the K=1024 dot
// (coalesced float4 W1 row reads), butterfly-reduce, lane j keeps output j.
__global__ __launch_bounds__(256) void gemm1_silu_k(const float* __restrict__ pooled,
                                                    const float* __restrict__ W1,
                                                    const float* __restrict__ b1,
                                                    float* __restrict__ hbuf) {
    int b  = blockIdx.x >> 4;
    int oc = blockIdx.x & 15;
    int t  = threadIdx.x;
    int wave = t >> 6, lane = t & 63;
    __shared__ vf4 spool[HH / 4];
    spool[t] = reinterpret_cast<const vf4*>(pooled + (size_t)b * HH)[t];
    __syncthreads();
    int obase = oc * 64 + wave * 16;
    float myz = 0.f;
    for (int j = 0; j < 16; ++j) {
        const vf4* wrow = reinterpret_cast<const vf4*>(W1 + (size_t)(obase + j) * HH);
        float s = 0.f;
        #pragma unroll
        for (int k = 0; k < 4; ++k) {
            vf4 wv = wrow[lane + 64 * k];
            vf4 pv = spool[lane + 64 * k];
            s += wv.x * pv.x + wv.y * pv.y + wv.z * pv.z + wv.w * pv.w;
        }
        #pragma unroll
        for (int off = 32; off; off >>= 1) s += __shfl_xor(s, off);
        if (lane == j) myz = s;   // lane j (0..15) owns output obase+j
    }
    if (lane < 16) {
        int o = obase + lane;
        float z = myz + b1[o];
        hbuf[(size_t)b * HH + o] = z / (1.f + expf(-z));   // silu
    }
}

// ---------------- Kernel 4: logits, softmax, bit allocation ----------------
// grid = BB blocks, 256 threads (4 waves). Wave w computes logits p=2w,2w+1
// with dual accumulators over shared h loads; epilogue on wave 0.
__global__ __launch_bounds__(256) void head_k(const float* __restrict__ hbuf,
                                              const float* __restrict__ W2,
                                              const float* __restrict__ b2,
                                              const float* __restrict__ temp_p,
                                              const int* __restrict__ budget_p,
                                              float* __restrict__ out) {
    int b = blockIdx.x;
    int t = threadIdx.x;
    int wave = t >> 6, lane = t & 63;
    __shared__ float slog[PP];

    {
        const vf4* hrow = reinterpret_cast<const vf4*>(hbuf + (size_t)b * HH);
        int p0 = wave * 2, p1 = wave * 2 + 1;
        const vf4* w0 = reinterpret_cast<const vf4*>(W2 + (size_t)p0 * HH);
        const vf4* w1 = reinterpret_cast<const vf4*>(W2 + (size_t)p1 * HH);
        float s0 = 0.f, s1 = 0.f;
        #pragma unroll
        for (int k = 0; k < 4; ++k) {
            vf4 hv = hrow[lane + 64 * k];
            vf4 a = w0[lane + 64 * k];
            vf4 c = w1[lane + 64 * k];
            s0 += a.x * hv.x + a.y * hv.y + a.z * hv.z + a.w * hv.w;
            s1 += c.x * hv.x + c.y * hv.y + c.z * hv.z + c.w * hv.w;
        }
        #pragma unroll
        for (int off = 32; off; off >>= 1) {
            s0 += __shfl_xor(s0, off);
            s1 += __shfl_xor(s1, off);
        }
        if (lane == 0) {
            slog[p0] = s0 + b2[p0];
            slog[p1] = s1 + b2[p1];
        }
    }
    __syncthreads();
    if (wave != 0) return;

    // epilogue replicated on wave-0 lanes (identical values)
    float logit[PP];
    #pragma unroll
    for (int p = 0; p < PP; ++p) logit[p] = slog[p];
    float temp = fminf(fmaxf(temp_p[0], 0.1f), 5.0f);
    float budget = (float)budget_p[0];
    float inv_t = 1.0f / temp;
    float m = -INFINITY;
    #pragma unroll
    for (int p = 0; p < PP; ++p) { logit[p] *= inv_t; m = fmaxf(m, logit[p]); }
    float e[PP], se = 0.f;
    #pragma unroll
    for (int p = 0; p < PP; ++p) { e[p] = expf(logit[p] - m); se += e[p]; }
    float probs[PP];
    float inv_se = 1.0f / se;
    #pragma unroll
    for (int p = 0; p < PP; ++p) probs[p] = e[p] * inv_se;

    float x[PP], sx = 0.f;
    #pragma unroll
    for (int p = 0; p < PP; ++p) {
        x[p] = fminf(fmaxf(probs[p] * budget, 2.0f), 8.0f);
        sx += x[p];
    }
    float r = budget / (sx + 1e-8f);
    float bits[PP], sb = 0.f;
    #pragma unroll
    for (int p = 0; p < PP; ++p) {
        x[p] *= r;
        bits[p] = rintf(x[p]);   // round-half-even == jnp.round
        sb += bits[p];
    }
    float diff = truncf(budget - sb);
    if (diff != 0.f) {
        int idx = 0;
        if (diff > 0.f) {
            float best = bits[0];
            for (int p = 1; p < PP; ++p) if (bits[p] > best) { best = bits[p]; idx = p; }
        } else {
            float best = bits[0];
            for (int p = 1; p < PP; ++p) if (bits[p] < best) { best = bits[p]; idx = p; }
        }
        bits[idx] = fminf(fmaxf(bits[idx] + diff, 2.0f), 8.0f);
    }

    int lane0 = t;  // wave 0: t==lane
    if (lane0 < PP)            out[b * PP + lane0] = bits[lane0];
    else if (lane0 < 2 * PP)   out[BB * PP + b * PP + (lane0 - PP)] = probs[lane0 - PP];
}

extern "C" void kernel_launch(void* const* d_in, const int* in_sizes, int n_in,
                              void* d_out, int out_size, void* d_ws, size_t ws_size,
                              hipStream_t stream) {
    const float* hs     = (const float*)d_in[0];
    const float* W1     = (const float*)d_in[1];
    const float* b1     = (const float*)d_in[2];
    const float* W2     = (const float*)d_in[3];
    const float* b2     = (const float*)d_in[4];
    const float* temp   = (const float*)d_in[5];
    const int*   budget = (const int*)d_in[6];
    float* out = (float*)d_out;

    float* ws     = (float*)d_ws;
    float* part   = ws;                                  // BB*SPLIT*HH floats (8 MB)
    float* pooled = ws + (size_t)BB * SPLIT * HH;        // BB*HH floats
    float* hbuf   = pooled + (size_t)BB * HH;            // BB*HH floats

    hipLaunchKernelGGL(pool_partial_k, dim3(BB * SPLIT), dim3(256), 0, stream, hs, part);
    hipLaunchKernelGGL(pool_finish_k,  dim3(BB * HH / 4 / 256), dim3(256), 0, stream, part, pooled);
    hipLaunchKernelGGL(gemm1_silu_k,   dim3(BB * 16), dim3(256), 0, stream, pooled, W1, b1, hbuf);
    hipLaunchKernelGGL(head_k,         dim3(BB), dim3(256), 0, stream, hbuf, W2, b2, temp, budget, out);
}

// Round 4
// 102.628 us; speedup vs baseline: 1.3160x; 1.0385x over previous
//
#include <hip/hip_runtime.h>
#include <math.h>

#define BB 64
#define SS 2048
#define HH 1024
#define PP 8
#define SPLIT 16
#define ROWS (SS / SPLIT)   // 128

typedef float vf4 __attribute__((ext_vector_type(4)));

// ---------------- Kernel 1: partial mean-pool over S ----------------
// grid = BB*SPLIT (1024) blocks, 256 threads. Each block sums ROWS=128 rows of
// one (b, s-chunk) into a partial row in workspace. Nontemporal float4 loads;
// two accumulator chains, 8 loads in flight.
__global__ __launch_bounds__(256) void pool_partial_k(const float* __restrict__ hs,
                                                      float* __restrict__ part) {
    int blk = blockIdx.x;
    int b  = blk / SPLIT;
    int sp = blk % SPLIT;
    int t  = threadIdx.x;
    const vf4* base = reinterpret_cast<const vf4*>(
        hs + (size_t)b * SS * HH + (size_t)sp * ROWS * HH);
    vf4 acc0 = (vf4)0.f;
    vf4 acc1 = (vf4)0.f;
    #pragma unroll 4
    for (int s = 0; s < ROWS; s += 2) {
        vf4 v0 = __builtin_nontemporal_load(&base[(size_t)s * (HH / 4) + t]);
        vf4 v1 = __builtin_nontemporal_load(&base[(size_t)(s + 1) * (HH / 4) + t]);
        acc0 += v0;
        acc1 += v1;
    }
    reinterpret_cast<vf4*>(part)[(size_t)blk * (HH / 4) + t] = acc0 + acc1;
}

// ---------------- Kernel 2: fused pool-finish + GEMM1 + SiLU ----------------
// grid = 256 blocks: (bg in 0..15) x (oc in 0..15). 512 threads = 8 waves.
// Block handles batch rows b = 4*bg..4*bg+3 and outputs o = 64*oc..64*oc+63.
// Stage: sum 16 partials -> 4 pooled rows in LDS (16 KB).
// Dot: 16-lane K-split, 4 output rows concurrent per wave (one per lane group),
// 4 batch accumulators per lane, 4-level butterfly within the 16-lane group.
__global__ __launch_bounds__(512) void gemm_fused_k(const float* __restrict__ part,
                                                    const float* __restrict__ W1,
                                                    const float* __restrict__ b1,
                                                    float* __restrict__ hbuf) {
    int bg = blockIdx.x >> 4;
    int oc = blockIdx.x & 15;
    int t  = threadIdx.x;            // 0..511
    int wave = t >> 6, lane = t & 63;
    __shared__ vf4 spool[4][HH / 4];

    // ---- pool finish: pooled rows 4*bg..4*bg+3 from partials ----
    {
        int c  = t & 255;
        int r0 = t >> 8;             // 0..1
        #pragma unroll
        for (int rr = 0; rr < 2; ++rr) {
            int r = r0 + 2 * rr;     // 0..3
            int b = bg * 4 + r;
            const vf4* pb = reinterpret_cast<const vf4*>(part) +
                            (size_t)b * SPLIT * (HH / 4) + c;
            vf4 s = (vf4)0.f;
            #pragma unroll
            for (int sp = 0; sp < SPLIT; ++sp)
                s += pb[(size_t)sp * (HH / 4)];
            spool[r][c] = s * (1.0f / (float)SS);
        }
    }
    __syncthreads();

    // ---- GEMM: wave computes outputs w*8..w*8+7 (within oc chunk) x 4 b ----
    int g = lane >> 4;               // 0..3: output-row group
    int q = lane & 15;               // K-split index within group
    #pragma unroll
    for (int i = 0; i < 2; ++i) {
        int o = oc * 64 + wave * 8 + i * 4 + g;
        const vf4* wrow = reinterpret_cast<const vf4*>(W1 + (size_t)o * HH);
        float s0 = 0.f, s1 = 0.f, s2 = 0.f, s3 = 0.f;
        #pragma unroll
        for (int k = 0; k < 16; ++k) {
            vf4 wv = wrow[q + 16 * k];
            vf4 p0 = spool[0][q + 16 * k];
            vf4 p1 = spool[1][q + 16 * k];
            vf4 p2 = spool[2][q + 16 * k];
            vf4 p3 = spool[3][q + 16 * k];
            s0 += wv.x * p0.x + wv.y * p0.y + wv.z * p0.z + wv.w * p0.w;
            s1 += wv.x * p1.x + wv.y * p1.y + wv.z * p1.z + wv.w * p1.w;
            s2 += wv.x * p2.x + wv.y * p2.y + wv.z * p2.z + wv.w * p2.w;
            s3 += wv.x * p3.x + wv.y * p3.y + wv.z * p3.z + wv.w * p3.w;
        }
        #pragma unroll
        for (int off = 1; off < 16; off <<= 1) {   // butterfly within 16-lane group
            s0 += __shfl_xor(s0, off);
            s1 += __shfl_xor(s1, off);
            s2 += __shfl_xor(s2, off);
            s3 += __shfl_xor(s3, off);
        }
        if (q < 4) {                 // lane q of group g writes batch row q
            float s = (q == 0) ? s0 : ((q == 1) ? s1 : ((q == 2) ? s2 : s3));
            int b = bg * 4 + q;
            float z = s + b1[o];
            hbuf[(size_t)b * HH + o] = z / (1.f + expf(-z));
        }
    }
}

// ---------------- Kernel 3: logits, softmax, bit allocation ----------------
// grid = BB blocks, 256 threads (4 waves). Wave w computes logits p=2w,2w+1.
__global__ __launch_bounds__(256) void head_k(const float* __restrict__ hbuf,
                                              const float* __restrict__ W2,
                                              const float* __restrict__ b2,
                                              const float* __restrict__ temp_p,
                                              const int* __restrict__ budget_p,
                                              float* __restrict__ out) {
    int b = blockIdx.x;
    int t = threadIdx.x;
    int wave = t >> 6, lane = t & 63;
    __shared__ float slog[PP];

    {
        const vf4* hrow = reinterpret_cast<const vf4*>(hbuf + (size_t)b * HH);
        int p0 = wave * 2, p1 = wave * 2 + 1;
        const vf4* w0 = reinterpret_cast<const vf4*>(W2 + (size_t)p0 * HH);
        const vf4* w1 = reinterpret_cast<const vf4*>(W2 + (size_t)p1 * HH);
        float s0 = 0.f, s1 = 0.f;
        #pragma unroll
        for (int k = 0; k < 4; ++k) {
            vf4 hv = hrow[lane + 64 * k];
            vf4 a = w0[lane + 64 * k];
            vf4 c = w1[lane + 64 * k];
            s0 += a.x * hv.x + a.y * hv.y + a.z * hv.z + a.w * hv.w;
            s1 += c.x * hv.x + c.y * hv.y + c.z * hv.z + c.w * hv.w;
        }
        #pragma unroll
        for (int off = 32; off; off >>= 1) {
            s0 += __shfl_xor(s0, off);
            s1 += __shfl_xor(s1, off);
        }
        if (lane == 0) {
            slog[p0] = s0 + b2[p0];
            slog[p1] = s1 + b2[p1];
        }
    }
    __syncthreads();
    if (wave != 0) return;

    float logit[PP];
    #pragma unroll
    for (int p = 0; p < PP; ++p) logit[p] = slog[p];
    float temp = fminf(fmaxf(temp_p[0], 0.1f), 5.0f);
    float budget = (float)budget_p[0];
    float inv_t = 1.0f / temp;
    float m = -INFINITY;
    #pragma unroll
    for (int p = 0; p < PP; ++p) { logit[p] *= inv_t; m = fmaxf(m, logit[p]); }
    float e[PP], se = 0.f;
    #pragma unroll
    for (int p = 0; p < PP; ++p) { e[p] = expf(logit[p] - m); se += e[p]; }
    float probs[PP];
    float inv_se = 1.0f / se;
    #pragma unroll
    for (int p = 0; p < PP; ++p) probs[p] = e[p] * inv_se;

    float x[PP], sx = 0.f;
    #pragma unroll
    for (int p = 0; p < PP; ++p) {
        x[p] = fminf(fmaxf(probs[p] * budget, 2.0f), 8.0f);
        sx += x[p];
    }
    float r = budget / (sx + 1e-8f);
    float bits[PP], sb = 0.f;
    #pragma unroll
    for (int p = 0; p < PP; ++p) {
        x[p] *= r;
        bits[p] = rintf(x[p]);   // round-half-even == jnp.round
        sb += bits[p];
    }
    float diff = truncf(budget - sb);
    if (diff != 0.f) {
        int idx = 0;
        if (diff > 0.f) {
            float best = bits[0];
            for (int p = 1; p < PP; ++p) if (bits[p] > best) { best = bits[p]; idx = p; }
        } else {
            float best = bits[0];
            for (int p = 1; p < PP; ++p) if (bits[p] < best) { best = bits[p]; idx = p; }
        }
        bits[idx] = fminf(fmaxf(bits[idx] + diff, 2.0f), 8.0f);
    }

    if (t < PP)            out[b * PP + t] = bits[t];
    else if (t < 2 * PP)   out[BB * PP + b * PP + (t - PP)] = probs[t - PP];
}

extern "C" void kernel_launch(void* const* d_in, const int* in_sizes, int n_in,
                              void* d_out, int out_size, void* d_ws, size_t ws_size,
                              hipStream_t stream) {
    const float* hs     = (const float*)d_in[0];
    const float* W1     = (const float*)d_in[1];
    const float* b1     = (const float*)d_in[2];
    const float* W2     = (const float*)d_in[3];
    const float* b2     = (const float*)d_in[4];
    const float* temp   = (const float*)d_in[5];
    const int*   budget = (const int*)d_in[6];
    float* out = (float*)d_out;

    float* ws   = (float*)d_ws;
    float* part = ws;                                 // BB*SPLIT*HH floats (4 MB)
    float* hbuf = ws + (size_t)BB * SPLIT * HH;       // BB*HH floats

    hipLaunchKernelGGL(pool_partial_k, dim3(BB * SPLIT), dim3(256), 0, stream, hs, part);
    hipLaunchKernelGGL(gemm_fused_k,   dim3(256), dim3(512), 0, stream, part, W1, b1, hbuf);
    hipLaunchKernelGGL(head_k,         dim3(BB), dim3(256), 0, stream, hbuf, W2, b2, temp, budget, out);
}